// Round 5
// baseline (183.620 us; speedup 1.0000x reference)
//
#include <hip/hip_runtime.h>

typedef __bf16 bf16;
typedef __attribute__((ext_vector_type(8))) __bf16 bf16x8;
typedef __attribute__((ext_vector_type(4))) __bf16 bf16x4;
typedef __attribute__((ext_vector_type(4))) float f32x4;

#define S 2048
#define DMODEL 512
#define NH 8
#define DH 64
#define DFF 2048
#define MAXLEN 16384
#define LN_EPS 1e-5f
#define NSP 8
#define CW (S / NSP)
#define BC 64
#define CST 0.18033688f  // (1/8) * log2(e)

__device__ __forceinline__ void gload16(const bf16* g, bf16* l) {
  __builtin_amdgcn_global_load_lds(
      (const __attribute__((address_space(1))) void*)g,
      (__attribute__((address_space(3))) void*)l, 16, 0, 0);
}

// ---------------- m97-style bf16 MFMA GEMM: C = A[M,K] @ Bt[N,K]^T (+bias)(+relu) ----------------
// flags: bit0 = relu, bit1 = bf16 output (else fp32), bit2 = scale z==0 output by CST
__global__ __launch_bounds__(256) void gemm_k(
    const bf16* __restrict__ A, long sAz, int lda,
    const bf16* __restrict__ B, long sBz, int ldb,
    void* __restrict__ C, long sCz, int ldc,
    const float* __restrict__ bias, long sBiasZ, int flags,
    int M, int N, int K)
{
  __shared__ bf16 lsA[128 * 32];
  __shared__ bf16 lsB[128 * 32];
  const int z = blockIdx.z;
  A += (long)z * sAz;
  B += (long)z * sBz;
  const int m0 = blockIdx.y * 128, n0 = blockIdx.x * 128;
  const int tid = threadIdx.x;
  const int lane = tid & 63, w = tid >> 6;
  const int wr = (w >> 1) * 64, wc = (w & 1) * 64;
  const int r15 = lane & 15, kg = lane >> 4;
  const int srow = lane >> 2, scol = (lane & 3) * 8;

  const bf16* Ag0 = A + (long)(m0 + 32 * w + srow) * lda + scol;
  const bf16* Ag1 = Ag0 + 16 * lda;
  const bf16* Bg0 = B + (long)(n0 + 32 * w + srow) * ldb + scol;
  const bf16* Bg1 = Bg0 + 16 * ldb;
  bf16* La0 = &lsA[(32 * w + srow) * 32 + scol];
  bf16* La1 = La0 + 16 * 32;
  bf16* Lb0 = &lsB[(32 * w + srow) * 32 + scol];
  bf16* Lb1 = Lb0 + 16 * 32;

  f32x4 acc[4][4] = {};
  for (int k0 = 0; k0 < K; k0 += 32) {
    gload16(Ag0 + k0, La0);
    gload16(Ag1 + k0, La1);
    gload16(Bg0 + k0, Lb0);
    gload16(Bg1 + k0, Lb1);
    __syncthreads();
    bf16x8 af[4], bfr[4];
#pragma unroll
    for (int mi = 0; mi < 4; ++mi) af[mi] = *(const bf16x8*)&lsA[(wr + mi * 16 + r15) * 32 + kg * 8];
#pragma unroll
    for (int ni = 0; ni < 4; ++ni) bfr[ni] = *(const bf16x8*)&lsB[(wc + ni * 16 + r15) * 32 + kg * 8];
    __builtin_amdgcn_s_setprio(1);
#pragma unroll
    for (int mi = 0; mi < 4; ++mi)
#pragma unroll
      for (int ni = 0; ni < 4; ++ni)
        acc[mi][ni] = __builtin_amdgcn_mfma_f32_16x16x32_bf16(af[mi], bfr[ni], acc[mi][ni], 0, 0, 0);
    __builtin_amdgcn_s_setprio(0);
    __syncthreads();
  }
  const float* bz = bias ? bias + (long)z * sBiasZ : nullptr;
  const float scl = ((flags & 4) && z == 0) ? CST : 1.f;
#pragma unroll
  for (int mi = 0; mi < 4; ++mi)
#pragma unroll
    for (int ni = 0; ni < 4; ++ni) {
      int col = n0 + wc + ni * 16 + r15;
      float bv = bz ? bz[col] : 0.f;
#pragma unroll
      for (int r = 0; r < 4; ++r) {
        int row = m0 + wr + mi * 16 + kg * 4 + r;
        float v = (acc[mi][ni][r] + bv) * scl;
        if (flags & 1) v = fmaxf(v, 0.f);
        if (flags & 2) ((bf16*)C)[(long)z * sCz + (long)row * ldc + col] = (bf16)v;
        else           ((float*)C)[(long)z * sCz + (long)row * ldc + col] = v;
      }
    }
}

// ---------------- fused attention v3: swapped QK layout (lane = one q-row) ----------------
// grid (32*NSP, NH): rb = bx>>3 (64-row block), sp = bx&7 (column slice of 256)
// Inputs pre-scaled by CST (Q and hence qer). Scores already in exp2 domain.
__global__ __launch_bounds__(256, 5) void attn_k(
    const bf16* __restrict__ qg, const bf16* __restrict__ kgl, const bf16* __restrict__ vtg,
    const bf16* __restrict__ qer,
    float* __restrict__ pO, float* __restrict__ pM, float* __restrict__ pL)
{
  __shared__ bf16 KP[64 * 72];    // K tile [c][k], reused as P[w][16][72]
  __shared__ bf16 Vl[64 * 72];    // V^T tile [d][c]
  __shared__ bf16 Band[64 * 88];  // qer band per row, stride 88 (2-way banks = free)
  const int bx = blockIdx.x, h = blockIdx.y;
  const int rb = bx >> 3, sp = bx & 7;
  const int r0 = rb * 64;
  const int cb = sp * CW;
  const int tid = threadIdx.x, lane = tid & 63, w = tid >> 6;
  const int r15 = lane & 15, g = lane >> 4;
  const long hb = (long)h * S * S;

  // persistent Q frags (B-operand): row = r0+16w+r15, k = g*8..
  bf16x8 qf0, qf1;
  {
    const bf16* qrow = qg + (long)(r0 + w * 16 + r15) * DMODEL + h * DH;
    qf0 = *(const bf16x8*)&qrow[g * 8];
    qf1 = *(const bf16x8*)&qrow[32 + g * 8];
  }
  f32x4 Oacc[4] = {};
  float m2 = -1e30f, l2 = 0.f;   // state for q-row (w*16 + r15)

  const int myrow = w * 16 + r15;        // softmax-state row (block-local)
  const int rg = r0 + myrow;             // global q-row for this lane's scores
  const int boff = (S - 2 - rg) & 7;
  const int rowb = myrow * 88;
  const int oRow = r0 + w * 16 + 4 * g;  // Oacc row base (+r)
  const int kRow = tid >> 3, kCh = (tid & 7) * 8;

  for (int t = 0; t < CW / BC; ++t) {
    const int c0 = cb + t * BC;
    __syncthreads();
    // stage K tile [64][64] (pad-72 rows)
    *(bf16x8*)&KP[kRow * 72 + kCh]        = *(const bf16x8*)&kgl[(long)(c0 + kRow) * DMODEL + h * DH + kCh];
    *(bf16x8*)&KP[(kRow + 32) * 72 + kCh] = *(const bf16x8*)&kgl[(long)(c0 + kRow + 32) * DMODEL + h * DH + kCh];
    // stage V^T tile [64][64]
    *(bf16x8*)&Vl[kRow * 72 + kCh]        = *(const bf16x8*)&vtg[(long)(h * DH + kRow) * S + c0 + kCh];
    *(bf16x8*)&Vl[(kRow + 32) * 72 + kCh] = *(const bf16x8*)&vtg[(long)(h * DH + kRow + 32) * S + c0 + kCh];
    // stage qer band: row `row` covers flat qer[rg2*S + a .. a+88), a = (c0+S-2-rg2) & ~7
#pragma unroll
    for (int i = 0; i < 3; ++i) {
      int idx = tid + i * 256;
      if (i < 2 || idx < 704) {
        int row = idx / 11, ch = idx - row * 11;
        int rg2 = r0 + row;
        int a = (c0 + S - 2 - rg2) & ~7;
        *(bf16x8*)&Band[row * 88 + ch * 8] = *(const bf16x8*)&qer[hb + (long)rg2 * S + a + ch * 8];
      }
    }
    __syncthreads();

    // QK^T swapped: sc[ni][r] = score[q-row = myrow][k-col = ni*16 + 4g + r]
    f32x4 sc[4];
    __builtin_amdgcn_s_setprio(1);
#pragma unroll
    for (int ni = 0; ni < 4; ++ni) {
      bf16x8 k0f = *(const bf16x8*)&KP[(ni * 16 + r15) * 72 + g * 8];
      bf16x8 k1f = *(const bf16x8*)&KP[(ni * 16 + r15) * 72 + 32 + g * 8];
      f32x4 a = {};
      a = __builtin_amdgcn_mfma_f32_16x16x32_bf16(k0f, qf0, a, 0, 0, 0);
      a = __builtin_amdgcn_mfma_f32_16x16x32_bf16(k1f, qf1, a, 0, 0, 0);
      sc[ni] = a;
    }
    __builtin_amdgcn_s_setprio(0);

    // srel: branchless skew gather (pre-scaled, so plain add)
    const int dg = rg - c0;  // cl <= dg -> lower-tri; cl == dg+1 -> zero
#pragma unroll
    for (int ni = 0; ni < 4; ++ni)
#pragma unroll
      for (int r = 0; r < 4; ++r) {
        int cl = ni * 16 + 4 * g + r;
        int le = (cl <= dg) ? 1 : 0;
        float srel = (cl == dg + 1) ? 0.f : (float)Band[rowb + boff + cl + le];
        sc[ni][r] += srel;
      }

    // online softmax (base-2), per-lane row
    float tmax = sc[0][0];
#pragma unroll
    for (int ni = 0; ni < 4; ++ni)
#pragma unroll
      for (int r = 0; r < 4; ++r) tmax = fmaxf(tmax, sc[ni][r]);
    tmax = fmaxf(tmax, __shfl_xor(tmax, 16));
    tmax = fmaxf(tmax, __shfl_xor(tmax, 32));

    float mn = fmaxf(m2, tmax);
    float al = exp2f(m2 - mn);
    m2 = mn;
    float tsum = 0.f;
#pragma unroll
    for (int ni = 0; ni < 4; ++ni)
#pragma unroll
      for (int r = 0; r < 4; ++r) {
        float p = exp2f(sc[ni][r] - m2);
        sc[ni][r] = p;
        tsum += p;
      }
    tsum += __shfl_xor(tsum, 16);
    tsum += __shfl_xor(tsum, 32);
    l2 = l2 * al + tsum;

    // rescale Oacc: alpha for Oacc row (4g+r) lives at lane with r15 = 4g+r
#pragma unroll
    for (int r = 0; r < 4; ++r) {
      float alr = __shfl(al, (lane & 48) | (4 * (lane >> 4) + r));
#pragma unroll
      for (int no = 0; no < 4; ++no) Oacc[no][r] *= alr;
    }

    __syncthreads(); // all waves done reading K tile -> safe to overwrite with P

    // write P (packed b64: 4 consecutive k-cols per ni), then PV
    bf16* Pw = &KP[w * 16 * 72];
#pragma unroll
    for (int ni = 0; ni < 4; ++ni) {
      bf16x4 pv = { (bf16)sc[ni][0], (bf16)sc[ni][1], (bf16)sc[ni][2], (bf16)sc[ni][3] };
      *(bf16x4*)&Pw[r15 * 72 + ni * 16 + 4 * g] = pv;
    }

    __builtin_amdgcn_s_setprio(1);
#pragma unroll
    for (int kc = 0; kc < 2; ++kc) {
      bf16x8 af = *(const bf16x8*)&Pw[r15 * 72 + kc * 32 + g * 8];
#pragma unroll
      for (int no = 0; no < 4; ++no) {
        bf16x8 bv = *(const bf16x8*)&Vl[(no * 16 + r15) * 72 + kc * 32 + g * 8];
        Oacc[no] = __builtin_amdgcn_mfma_f32_16x16x32_bf16(af, bv, Oacc[no], 0, 0, 0);
      }
    }
    __builtin_amdgcn_s_setprio(0);
  }

  // write partials
  const long ob = ((long)sp * NH + h) * S * DH;
#pragma unroll
  for (int no = 0; no < 4; ++no)
#pragma unroll
    for (int r = 0; r < 4; ++r)
      pO[ob + (long)(oRow + r) * DH + no * 16 + r15] = Oacc[no][r];
  if (g == 0) {
    const long sb = ((long)sp * NH + h) * S;
    pM[sb + rg] = m2;
    pL[sb + rg] = l2;
  }
}

// ---------------- merge the NSP column-slice partials -> sa[r][DMODEL] (f32) ----------------
__global__ __launch_bounds__(256) void merge_k(
    const float* __restrict__ pO, const float* __restrict__ pM, const float* __restrict__ pL,
    float* __restrict__ sa)
{
  int i = blockIdx.x * 256 + threadIdx.x;
  int r = i >> 9, col = i & 511;
  int h = col >> 6, d = col & 63;
  long i0 = (long)h * S + r;
  float mm = -1e30f;
  float ms[NSP];
#pragma unroll
  for (int s = 0; s < NSP; ++s) { ms[s] = pM[(long)s * NH * S + i0]; mm = fmaxf(mm, ms[s]); }
  float num = 0.f, den = 0.f;
#pragma unroll
  for (int s = 0; s < NSP; ++s) {
    float e = exp2f(ms[s] - mm);
    den += pL[(long)s * NH * S + i0] * e;
    num += pO[(long)s * NH * S * DH + i0 * DH + d] * e;
  }
  sa[(long)r * DMODEL + col] = num / den;
}

// ---------------- layernorms ----------------
__device__ __forceinline__ float blk_sum(float v, float* red) {
  for (int o = 32; o; o >>= 1) v += __shfl_xor(v, o);
  int tid = threadIdx.x;
  if ((tid & 63) == 0) red[tid >> 6] = v;
  __syncthreads();
  v = red[0] + red[1] + red[2] + red[3];
  __syncthreads();
  return v;
}

__global__ __launch_bounds__(256) void ln1_k(
    const float* __restrict__ src, const float* __restrict__ sa,
    const float* __restrict__ g, const float* __restrict__ be, bf16* __restrict__ y)
{
  __shared__ float red[4];
  const int row = blockIdx.x;
  const int b = row >> 11, s2 = row & 2047;
  const float* xs = src + (long)s2 * (2 * DMODEL) + b * DMODEL;
  const float* ss = sa + (long)s2 * DMODEL;
  const int tid = threadIdx.x;
  float a0 = xs[tid] + ss[tid];
  float a1 = xs[tid + 256] + ss[tid + 256];
  float sum = blk_sum(a0 + a1, red);
  float sq  = blk_sum(a0 * a0 + a1 * a1, red);
  float mu = sum * (1.f / DMODEL);
  float var = sq * (1.f / DMODEL) - mu * mu;
  float rs = rsqrtf(var + LN_EPS);
  y[(long)row * DMODEL + tid]       = (bf16)((a0 - mu) * rs * g[tid] + be[tid]);
  y[(long)row * DMODEL + tid + 256] = (bf16)((a1 - mu) * rs * g[tid + 256] + be[tid + 256]);
}

// out = LN( y + sum_4(pFF) + b2 ) ; pFF are split-K partials
__global__ __launch_bounds__(256) void ln2_k(
    const bf16* __restrict__ y, const float* __restrict__ pFF, long pStride,
    const float* __restrict__ b2,
    const float* __restrict__ g, const float* __restrict__ be, float* __restrict__ out)
{
  __shared__ float red[4];
  const int row = blockIdx.x;
  const int b = row >> 11, s2 = row & 2047;
  const int tid = threadIdx.x;
  long i0 = (long)row * DMODEL + tid;
  long i1 = i0 + 256;
  float f0 = pFF[i0] + pFF[i0 + pStride] + pFF[i0 + 2 * pStride] + pFF[i0 + 3 * pStride] + b2[tid];
  float f1 = pFF[i1] + pFF[i1 + pStride] + pFF[i1 + 2 * pStride] + pFF[i1 + 3 * pStride] + b2[tid + 256];
  float a0 = (float)y[i0] + f0;
  float a1 = (float)y[i1] + f1;
  float sum = blk_sum(a0 + a1, red);
  float sq  = blk_sum(a0 * a0 + a1 * a1, red);
  float mu = sum * (1.f / DMODEL);
  float var = sq * (1.f / DMODEL) - mu * mu;
  float rs = rsqrtf(var + LN_EPS);
  float* o = out + (long)s2 * (2 * DMODEL) + b * DMODEL;
  o[tid]       = (a0 - mu) * rs * g[tid] + be[tid];
  o[tid + 256] = (a1 - mu) * rs * g[tid + 256] + be[tid + 256];
}

// ---------------- converts / transposes ----------------
__global__ __launch_bounds__(256) void conv_x0_k(const float* __restrict__ src, bf16* __restrict__ x0b)
{
  long i = (long)blockIdx.x * 256 + threadIdx.x;
  int s2 = (int)(i >> 9), d = (int)(i & 511);
  x0b[i] = (bf16)src[(long)s2 * (2 * DMODEL) + d];
}

__global__ __launch_bounds__(256) void conv_er_k(const float* __restrict__ Er, bf16* __restrict__ erS)
{
  long i = (long)blockIdx.x * 256 + threadIdx.x;
  erS[i] = (bf16)Er[(long)(MAXLEN - S) * DH + i];
}

__global__ __launch_bounds__(256) void pack_bias_k(
    const float* __restrict__ a, const float* __restrict__ b, const float* __restrict__ c,
    float* __restrict__ o)
{
  int t = blockIdx.x * 256 + threadIdx.x;
  o[t] = t < 512 ? a[t] : (t < 1024 ? b[t - 512] : c[t - 1024]);
}

__global__ void tr_f2b_k(const float* __restrict__ in, bf16* __restrict__ out, int R, int Cn)
{
  __shared__ float t[32][33];
  int c0 = blockIdx.x * 32, r0 = blockIdx.y * 32;
  int tx = threadIdx.x, ty = threadIdx.y;
#pragma unroll
  for (int i = 0; i < 32; i += 8) t[ty + i][tx] = in[(long)(r0 + ty + i) * Cn + c0 + tx];
  __syncthreads();
#pragma unroll
  for (int i = 0; i < 32; i += 8) out[(long)(c0 + ty + i) * R + r0 + tx] = (bf16)t[tx][ty + i];
}

__global__ void tr_b2b_k(const bf16* __restrict__ in, bf16* __restrict__ out, int R, int Cn)
{
  __shared__ bf16 t[32][34];
  int c0 = blockIdx.x * 32, r0 = blockIdx.y * 32;
  int tx = threadIdx.x, ty = threadIdx.y;
#pragma unroll
  for (int i = 0; i < 32; i += 8) t[ty + i][tx] = in[(long)(r0 + ty + i) * Cn + c0 + tx];
  __syncthreads();
#pragma unroll
  for (int i = 0; i < 32; i += 8) out[(long)(c0 + ty + i) * R + r0 + tx] = t[tx][ty + i];
}

// ---------------- host launch ----------------
extern "C" void kernel_launch(void* const* d_in, const int* in_sizes, int n_in,
                              void* d_out, int out_size, void* d_ws, size_t ws_size,
                              hipStream_t stream)
{
  const float* src = (const float*)d_in[0];
  const float* Wq  = (const float*)d_in[1];
  const float* bq  = (const float*)d_in[2];
  const float* Wk  = (const float*)d_in[3];
  const float* bk  = (const float*)d_in[4];
  const float* Wv  = (const float*)d_in[5];
  const float* bv  = (const float*)d_in[6];
  const float* Er  = (const float*)d_in[7];
  const float* W1  = (const float*)d_in[8];
  const float* b1  = (const float*)d_in[9];
  const float* W2  = (const float*)d_in[10];
  const float* b2  = (const float*)d_in[11];
  const float* g1  = (const float*)d_in[12];
  const float* be1 = (const float*)d_in[13];
  const float* g2  = (const float*)d_in[14];
  const float* be2 = (const float*)d_in[15];

  char* wp = (char*)d_ws;
  auto alloc = [&](size_t bytes) { char* p = wp; wp += (bytes + 255) & ~(size_t)255; return p; };

  bf16* x0b   = (bf16*)alloc((size_t)S * DMODEL * 2);
  bf16* wqkvT = (bf16*)alloc((size_t)3 * DMODEL * DMODEL * 2);
  float* bqkv = (float*)alloc((size_t)3 * DMODEL * 4);
  bf16* w1T   = (bf16*)alloc((size_t)DFF * DMODEL * 2);
  bf16* w2T   = (bf16*)alloc((size_t)DMODEL * DFF * 2);
  bf16* erS   = (bf16*)alloc((size_t)S * DH * 2);
  bf16* qkvb  = (bf16*)alloc((size_t)3 * S * DMODEL * 2);
  bf16* vt    = (bf16*)alloc((size_t)DMODEL * S * 2);
  bf16* qer   = (bf16*)alloc((size_t)NH * S * S * 2);
  float* pO   = (float*)alloc((size_t)NSP * NH * S * DH * 4);
  float* pM   = (float*)alloc((size_t)NSP * NH * S * 4);
  float* pL   = (float*)alloc((size_t)NSP * NH * S * 4);
  float* sa   = (float*)alloc((size_t)S * DMODEL * 4);
  bf16* yb    = (bf16*)alloc((size_t)2 * S * DMODEL * 2);
  bf16* h1    = (bf16*)alloc((size_t)2 * S * DFF * 2);
  float* pFF  = (float*)alloc((size_t)4 * 2 * S * DMODEL * 4);

  const long MN2 = (long)2 * S * DMODEL;
  dim3 tb(32, 8);

  conv_x0_k<<<(S * DMODEL) / 256, 256, 0, stream>>>(src, x0b);
  conv_er_k<<<(S * DH) / 256, 256, 0, stream>>>(Er, erS);
  tr_f2b_k<<<dim3(DMODEL / 32, DMODEL / 32), tb, 0, stream>>>(Wq, wqkvT, DMODEL, DMODEL);
  tr_f2b_k<<<dim3(DMODEL / 32, DMODEL / 32), tb, 0, stream>>>(Wk, wqkvT + DMODEL * DMODEL, DMODEL, DMODEL);
  tr_f2b_k<<<dim3(DMODEL / 32, DMODEL / 32), tb, 0, stream>>>(Wv, wqkvT + 2 * DMODEL * DMODEL, DMODEL, DMODEL);
  pack_bias_k<<<6, 256, 0, stream>>>(bq, bk, bv, bqkv);
  tr_f2b_k<<<dim3(DFF / 32, DMODEL / 32), tb, 0, stream>>>(W1, w1T, DMODEL, DFF);
  tr_f2b_k<<<dim3(DMODEL / 32, DFF / 32), tb, 0, stream>>>(W2, w2T, DFF, DMODEL);

  // QKV (batch 0 only), batched z=3; z==0 (Q) pre-scaled by CST
  gemm_k<<<dim3(4, 16, 3), 256, 0, stream>>>(
      x0b, 0, DMODEL, wqkvT, (long)DMODEL * DMODEL, DMODEL,
      qkvb, (long)S * DMODEL, DMODEL, bqkv, DMODEL, 6, S, DMODEL, DMODEL);

  const bf16* qb = qkvb;
  const bf16* kb = qkvb + (long)S * DMODEL;
  const bf16* vb = qkvb + (long)2 * S * DMODEL;

  // V^T
  tr_b2b_k<<<dim3(DMODEL / 32, S / 32), tb, 0, stream>>>(vb, vt, S, DMODEL);

  // QEr[h] = Qscaled_h @ ErS^T  (pre-scaled qer)
  gemm_k<<<dim3(16, 16, 8), 256, 0, stream>>>(
      qb, DH, DMODEL, erS, 0, DH, qer, (long)S * S, S, nullptr, 0, 2, S, S, DH);

  // fused attention
  attn_k<<<dim3(32 * NSP, NH), 256, 0, stream>>>(qb, kb, vt, qer, pO, pM, pL);
  merge_k<<<(S * DMODEL) / 256, 256, 0, stream>>>(pO, pM, pL, sa);

  // LN1 -> y (bf16)
  ln1_k<<<2 * S, 256, 0, stream>>>(src, sa, g1, be1, yb);

  // FFN1: y @ W1^T + b1, relu, bf16
  gemm_k<<<dim3(DFF / 128, (2 * S) / 128, 1), 256, 0, stream>>>(
      yb, 0, DMODEL, w1T, 0, DMODEL, h1, 0, DFF, b1, 0, 3, 2 * S, DFF, DMODEL);

  // FFN2 split-K=4: partials in pFF[z], bias added in ln2
  gemm_k<<<dim3(DMODEL / 128, (2 * S) / 128, 4), 256, 0, stream>>>(
      h1, 512, DFF, w2T, 512, DFF, pFF, MN2, DMODEL, nullptr, 0, 0, 2 * S, DMODEL, 512);

  // LN2 (+partial-sum +b2) -> out
  ln2_k<<<2 * S, 256, 0, stream>>>(yb, pFF, MN2, b2, g2, be2, (float*)d_out);
}

// Round 6
// 178.170 us; speedup vs baseline: 1.0306x; 1.0306x over previous
//
#include <hip/hip_runtime.h>

typedef __bf16 bf16;
typedef __attribute__((ext_vector_type(8))) __bf16 bf16x8;
typedef __attribute__((ext_vector_type(4))) __bf16 bf16x4;
typedef __attribute__((ext_vector_type(4))) float f32x4;

#define S 2048
#define DMODEL 512
#define NH 8
#define DH 64
#define DFF 2048
#define MAXLEN 16384
#define LN_EPS 1e-5f
#define NSP 8
#define CW (S / NSP)
#define BC 64
#define CST 0.18033688f  // (1/8) * log2(e)

__device__ __forceinline__ void gload16(const bf16* g, bf16* l) {
  __builtin_amdgcn_global_load_lds(
      (const __attribute__((address_space(1))) void*)g,
      (__attribute__((address_space(3))) void*)l, 16, 0, 0);
}

// ---------------- m97-style bf16 MFMA GEMM: C = A[M,K] @ Bt[N,K]^T (+bias)(+relu) ----------------
// flags: bit0 = relu, bit1 = bf16 output (else fp32), bit2 = scale z==0 output by CST
__global__ __launch_bounds__(256) void gemm_k(
    const bf16* __restrict__ A, long sAz, int lda,
    const bf16* __restrict__ B, long sBz, int ldb,
    void* __restrict__ C, long sCz, int ldc,
    const float* __restrict__ bias, long sBiasZ, int flags,
    int M, int N, int K)
{
  __shared__ bf16 lsA[128 * 32];
  __shared__ bf16 lsB[128 * 32];
  const int z = blockIdx.z;
  A += (long)z * sAz;
  B += (long)z * sBz;
  const int m0 = blockIdx.y * 128, n0 = blockIdx.x * 128;
  const int tid = threadIdx.x;
  const int lane = tid & 63, w = tid >> 6;
  const int wr = (w >> 1) * 64, wc = (w & 1) * 64;
  const int r15 = lane & 15, kg = lane >> 4;
  const int srow = lane >> 2, scol = (lane & 3) * 8;

  const bf16* Ag0 = A + (long)(m0 + 32 * w + srow) * lda + scol;
  const bf16* Ag1 = Ag0 + 16 * lda;
  const bf16* Bg0 = B + (long)(n0 + 32 * w + srow) * ldb + scol;
  const bf16* Bg1 = Bg0 + 16 * ldb;
  bf16* La0 = &lsA[(32 * w + srow) * 32 + scol];
  bf16* La1 = La0 + 16 * 32;
  bf16* Lb0 = &lsB[(32 * w + srow) * 32 + scol];
  bf16* Lb1 = Lb0 + 16 * 32;

  f32x4 acc[4][4] = {};
  for (int k0 = 0; k0 < K; k0 += 32) {
    gload16(Ag0 + k0, La0);
    gload16(Ag1 + k0, La1);
    gload16(Bg0 + k0, Lb0);
    gload16(Bg1 + k0, Lb1);
    __syncthreads();
    bf16x8 af[4], bfr[4];
#pragma unroll
    for (int mi = 0; mi < 4; ++mi) af[mi] = *(const bf16x8*)&lsA[(wr + mi * 16 + r15) * 32 + kg * 8];
#pragma unroll
    for (int ni = 0; ni < 4; ++ni) bfr[ni] = *(const bf16x8*)&lsB[(wc + ni * 16 + r15) * 32 + kg * 8];
    __builtin_amdgcn_s_setprio(1);
#pragma unroll
    for (int mi = 0; mi < 4; ++mi)
#pragma unroll
      for (int ni = 0; ni < 4; ++ni)
        acc[mi][ni] = __builtin_amdgcn_mfma_f32_16x16x32_bf16(af[mi], bfr[ni], acc[mi][ni], 0, 0, 0);
    __builtin_amdgcn_s_setprio(0);
    __syncthreads();
  }
  const float* bz = bias ? bias + (long)z * sBiasZ : nullptr;
  const float scl = ((flags & 4) && z == 0) ? CST : 1.f;
#pragma unroll
  for (int mi = 0; mi < 4; ++mi)
#pragma unroll
    for (int ni = 0; ni < 4; ++ni) {
      int col = n0 + wc + ni * 16 + r15;
      float bv = bz ? bz[col] : 0.f;
#pragma unroll
      for (int r = 0; r < 4; ++r) {
        int row = m0 + wr + mi * 16 + kg * 4 + r;
        float v = (acc[mi][ni][r] + bv) * scl;
        if (flags & 1) v = fmaxf(v, 0.f);
        if (flags & 2) ((bf16*)C)[(long)z * sCz + (long)row * ldc + col] = (bf16)v;
        else           ((float*)C)[(long)z * sCz + (long)row * ldc + col] = v;
      }
    }
}

// ---------------- fused attention v4 ----------------
// swapped QK (lane = one q-row), swapped PV (accumulate O^T, alpha is lane-local),
// per-wave P buffer (2 barriers/tile), T14 reg-prefetch of next tile's K/V/Band.
// grid (32*NSP, NH): rb = bx>>3 (64-row block), sp = bx&7 (column slice of 256)
// Inputs pre-scaled by CST (Q and hence qer). Scores already in exp2 domain.
__global__ __launch_bounds__(256, 4) void attn_k(
    const bf16* __restrict__ qg, const bf16* __restrict__ kgl, const bf16* __restrict__ vtg,
    const bf16* __restrict__ qer,
    float* __restrict__ pO, float* __restrict__ pM, float* __restrict__ pL)
{
  __shared__ bf16 Kl[64 * 72];      // K tile [c][k]
  __shared__ bf16 Vl[64 * 72];      // V^T tile [d][c]
  __shared__ bf16 Band[64 * 88];    // qer band per row, stride 88
  __shared__ bf16 Pl[4][16 * 72];   // per-wave P [q-local][c]
  const int bx = blockIdx.x, h = blockIdx.y;
  const int rb = bx >> 3, sp = bx & 7;
  const int r0 = rb * 64;
  const int cb = sp * CW;
  const int tid = threadIdx.x, lane = tid & 63, w = tid >> 6;
  const int r15 = lane & 15, g = lane >> 4;
  const long hb = (long)h * S * S;

  // persistent Q frags (B-operand of QK): row = r0+16w+r15, k = g*8..
  bf16x8 qf0, qf1;
  {
    const bf16* qrow = qg + (long)(r0 + w * 16 + r15) * DMODEL + h * DH;
    qf0 = *(const bf16x8*)&qrow[g * 8];
    qf1 = *(const bf16x8*)&qrow[32 + g * 8];
  }
  f32x4 Oacc[4] = {};           // O^T: Oacc[no][r] = O[q = w*16+r15][d = no*16+4g+r]
  float m2 = -1e30f, l2 = 0.f;  // softmax state for q-row w*16+r15

  const int myrow = w * 16 + r15;
  const int rg = r0 + myrow;
  const int boff = (S - 2 - rg) & 7;
  const int rowb = myrow * 88;

  // staging geometry
  const int kRow = tid >> 3, kCh = (tid & 7) * 8;
  int bR[3], bC[3];
#pragma unroll
  for (int i = 0; i < 3; ++i) { int idx = tid + i * 256; bR[i] = idx / 11; bC[i] = (idx - bR[i] * 11) * 8; }
  const bool b2v = tid < 192;  // 704 = 2*256 + 192 chunk-slots

  bf16x8 kf0, kf1, vf0, vf1, bd0, bd1, bd2;

  auto LOADR = [&](int c0) {
    kf0 = *(const bf16x8*)&kgl[(long)(c0 + kRow) * DMODEL + h * DH + kCh];
    kf1 = *(const bf16x8*)&kgl[(long)(c0 + kRow + 32) * DMODEL + h * DH + kCh];
    vf0 = *(const bf16x8*)&vtg[(long)(h * DH + kRow) * S + c0 + kCh];
    vf1 = *(const bf16x8*)&vtg[(long)(h * DH + kRow + 32) * S + c0 + kCh];
    {
      int rg2 = r0 + bR[0];
      int a = (c0 + S - 2 - rg2) & ~7;
      bd0 = *(const bf16x8*)&qer[hb + (long)rg2 * S + a + bC[0]];
    }
    {
      int rg2 = r0 + bR[1];
      int a = (c0 + S - 2 - rg2) & ~7;
      bd1 = *(const bf16x8*)&qer[hb + (long)rg2 * S + a + bC[1]];
    }
    if (b2v) {
      int rg2 = r0 + bR[2];
      int a = (c0 + S - 2 - rg2) & ~7;
      bd2 = *(const bf16x8*)&qer[hb + (long)rg2 * S + a + bC[2]];
    }
  };
  auto STORE = [&]() {
    *(bf16x8*)&Kl[kRow * 72 + kCh] = kf0;
    *(bf16x8*)&Kl[(kRow + 32) * 72 + kCh] = kf1;
    *(bf16x8*)&Vl[kRow * 72 + kCh] = vf0;
    *(bf16x8*)&Vl[(kRow + 32) * 72 + kCh] = vf1;
    *(bf16x8*)&Band[bR[0] * 88 + bC[0]] = bd0;
    *(bf16x8*)&Band[bR[1] * 88 + bC[1]] = bd1;
    if (b2v) *(bf16x8*)&Band[bR[2] * 88 + bC[2]] = bd2;
  };

  LOADR(cb);
#pragma unroll
  for (int t = 0; t < CW / BC; ++t) {
    const int c0 = cb + t * BC;
    __syncthreads();           // prev tile's LDS consumers done
    STORE();                   // regs -> LDS (waits its own vmcnt)
    if (t + 1 < CW / BC) LOADR(cb + (t + 1) * BC);  // prefetch next tile
    __syncthreads();           // LDS ready

    // QK^T swapped: sc[ni][r] = score[q = myrow][c-local = ni*16 + 4g + r]
    f32x4 sc[4];
    __builtin_amdgcn_s_setprio(1);
#pragma unroll
    for (int ni = 0; ni < 4; ++ni) {
      bf16x8 k0f = *(const bf16x8*)&Kl[(ni * 16 + r15) * 72 + g * 8];
      bf16x8 k1f = *(const bf16x8*)&Kl[(ni * 16 + r15) * 72 + 32 + g * 8];
      f32x4 a = {};
      a = __builtin_amdgcn_mfma_f32_16x16x32_bf16(k0f, qf0, a, 0, 0, 0);
      a = __builtin_amdgcn_mfma_f32_16x16x32_bf16(k1f, qf1, a, 0, 0, 0);
      sc[ni] = a;
    }
    __builtin_amdgcn_s_setprio(0);

    // srel: branchless skew gather (pre-scaled, so plain add)
    const int dg = rg - c0;
#pragma unroll
    for (int ni = 0; ni < 4; ++ni)
#pragma unroll
      for (int r = 0; r < 4; ++r) {
        int cl = ni * 16 + 4 * g + r;
        int le = (cl <= dg) ? 1 : 0;
        float srel = (cl == dg + 1) ? 0.f : (float)Band[rowb + boff + cl + le];
        sc[ni][r] += srel;
      }

    // online softmax (base-2), per-lane q-row
    float tmax = sc[0][0];
#pragma unroll
    for (int ni = 0; ni < 4; ++ni)
#pragma unroll
      for (int r = 0; r < 4; ++r) tmax = fmaxf(tmax, sc[ni][r]);
    tmax = fmaxf(tmax, __shfl_xor(tmax, 16));
    tmax = fmaxf(tmax, __shfl_xor(tmax, 32));

    float mn = fmaxf(m2, tmax);
    float al = exp2f(m2 - mn);
    m2 = mn;
    float tsum = 0.f;
#pragma unroll
    for (int ni = 0; ni < 4; ++ni)
#pragma unroll
      for (int r = 0; r < 4; ++r) {
        float p = exp2f(sc[ni][r] - m2);
        sc[ni][r] = p;
        tsum += p;
      }
    tsum += __shfl_xor(tsum, 16);
    tsum += __shfl_xor(tsum, 32);
    l2 = l2 * al + tsum;

    // rescale O^T: q-index of Oacc is r15 == softmax row -> own-lane alpha
#pragma unroll
    for (int no = 0; no < 4; ++no)
#pragma unroll
      for (int r = 0; r < 4; ++r) Oacc[no][r] *= al;

    // write P into own wave's buffer, then PV (no inter-wave barrier needed)
    bf16* Pw = Pl[w];
#pragma unroll
    for (int ni = 0; ni < 4; ++ni) {
      bf16x4 pv = { (bf16)sc[ni][0], (bf16)sc[ni][1], (bf16)sc[ni][2], (bf16)sc[ni][3] };
      *(bf16x4*)&Pw[r15 * 72 + ni * 16 + 4 * g] = pv;
    }

    __builtin_amdgcn_s_setprio(1);
#pragma unroll
    for (int kc = 0; kc < 2; ++kc) {
      bf16x8 pf = *(const bf16x8*)&Pw[r15 * 72 + kc * 32 + g * 8];
#pragma unroll
      for (int no = 0; no < 4; ++no) {
        bf16x8 av = *(const bf16x8*)&Vl[(no * 16 + r15) * 72 + kc * 32 + g * 8];
        Oacc[no] = __builtin_amdgcn_mfma_f32_16x16x32_bf16(av, pf, Oacc[no], 0, 0, 0);
      }
    }
    __builtin_amdgcn_s_setprio(0);
  }

  // write partials: O^T layout -> vectorized f32x4 stores
  const long ob = ((long)sp * NH + h) * S * DH;
  const long qrow_g = r0 + w * 16 + r15;
#pragma unroll
  for (int no = 0; no < 4; ++no)
    *(f32x4*)&pO[ob + qrow_g * DH + no * 16 + 4 * g] = Oacc[no];
  if (g == 0) {
    const long sb = ((long)sp * NH + h) * S;
    pM[sb + rg] = m2;
    pL[sb + rg] = l2;
  }
}

// ---------------- merge the NSP column-slice partials -> sa[r][DMODEL] (f32) ----------------
__global__ __launch_bounds__(256) void merge_k(
    const float* __restrict__ pO, const float* __restrict__ pM, const float* __restrict__ pL,
    float* __restrict__ sa)
{
  int i = blockIdx.x * 256 + threadIdx.x;
  int r = i >> 9, col = i & 511;
  int h = col >> 6, d = col & 63;
  long i0 = (long)h * S + r;
  float mm = -1e30f;
  float ms[NSP];
#pragma unroll
  for (int s = 0; s < NSP; ++s) { ms[s] = pM[(long)s * NH * S + i0]; mm = fmaxf(mm, ms[s]); }
  float num = 0.f, den = 0.f;
#pragma unroll
  for (int s = 0; s < NSP; ++s) {
    float e = exp2f(ms[s] - mm);
    den += pL[(long)s * NH * S + i0] * e;
    num += pO[(long)s * NH * S * DH + i0 * DH + d] * e;
  }
  sa[(long)r * DMODEL + col] = num / den;
}

// ---------------- layernorms ----------------
__device__ __forceinline__ float blk_sum(float v, float* red) {
  for (int o = 32; o; o >>= 1) v += __shfl_xor(v, o);
  int tid = threadIdx.x;
  if ((tid & 63) == 0) red[tid >> 6] = v;
  __syncthreads();
  v = red[0] + red[1] + red[2] + red[3];
  __syncthreads();
  return v;
}

__global__ __launch_bounds__(256) void ln1_k(
    const float* __restrict__ src, const float* __restrict__ sa,
    const float* __restrict__ g, const float* __restrict__ be, bf16* __restrict__ y)
{
  __shared__ float red[4];
  const int row = blockIdx.x;
  const int b = row >> 11, s2 = row & 2047;
  const float* xs = src + (long)s2 * (2 * DMODEL) + b * DMODEL;
  const float* ss = sa + (long)s2 * DMODEL;
  const int tid = threadIdx.x;
  float a0 = xs[tid] + ss[tid];
  float a1 = xs[tid + 256] + ss[tid + 256];
  float sum = blk_sum(a0 + a1, red);
  float sq  = blk_sum(a0 * a0 + a1 * a1, red);
  float mu = sum * (1.f / DMODEL);
  float var = sq * (1.f / DMODEL) - mu * mu;
  float rs = rsqrtf(var + LN_EPS);
  y[(long)row * DMODEL + tid]       = (bf16)((a0 - mu) * rs * g[tid] + be[tid]);
  y[(long)row * DMODEL + tid + 256] = (bf16)((a1 - mu) * rs * g[tid + 256] + be[tid + 256]);
}

// out = LN( y + sum_4(pFF) + b2 ) ; pFF are split-K partials
__global__ __launch_bounds__(256) void ln2_k(
    const bf16* __restrict__ y, const float* __restrict__ pFF, long pStride,
    const float* __restrict__ b2,
    const float* __restrict__ g, const float* __restrict__ be, float* __restrict__ out)
{
  __shared__ float red[4];
  const int row = blockIdx.x;
  const int b = row >> 11, s2 = row & 2047;
  const int tid = threadIdx.x;
  long i0 = (long)row * DMODEL + tid;
  long i1 = i0 + 256;
  float f0 = pFF[i0] + pFF[i0 + pStride] + pFF[i0 + 2 * pStride] + pFF[i0 + 3 * pStride] + b2[tid];
  float f1 = pFF[i1] + pFF[i1 + pStride] + pFF[i1 + 2 * pStride] + pFF[i1 + 3 * pStride] + b2[tid + 256];
  float a0 = (float)y[i0] + f0;
  float a1 = (float)y[i1] + f1;
  float sum = blk_sum(a0 + a1, red);
  float sq  = blk_sum(a0 * a0 + a1 * a1, red);
  float mu = sum * (1.f / DMODEL);
  float var = sq * (1.f / DMODEL) - mu * mu;
  float rs = rsqrtf(var + LN_EPS);
  float* o = out + (long)s2 * (2 * DMODEL) + b * DMODEL;
  o[tid]       = (a0 - mu) * rs * g[tid] + be[tid];
  o[tid + 256] = (a1 - mu) * rs * g[tid + 256] + be[tid + 256];
}

// ---------------- converts / transposes ----------------
__global__ __launch_bounds__(256) void conv_x0_k(const float* __restrict__ src, bf16* __restrict__ x0b)
{
  long i = (long)blockIdx.x * 256 + threadIdx.x;
  int s2 = (int)(i >> 9), d = (int)(i & 511);
  x0b[i] = (bf16)src[(long)s2 * (2 * DMODEL) + d];
}

__global__ __launch_bounds__(256) void conv_er_k(const float* __restrict__ Er, bf16* __restrict__ erS)
{
  long i = (long)blockIdx.x * 256 + threadIdx.x;
  erS[i] = (bf16)Er[(long)(MAXLEN - S) * DH + i];
}

__global__ __launch_bounds__(256) void pack_bias_k(
    const float* __restrict__ a, const float* __restrict__ b, const float* __restrict__ c,
    float* __restrict__ o)
{
  int t = blockIdx.x * 256 + threadIdx.x;
  o[t] = t < 512 ? a[t] : (t < 1024 ? b[t - 512] : c[t - 1024]);
}

__global__ void tr_f2b_k(const float* __restrict__ in, bf16* __restrict__ out, int R, int Cn)
{
  __shared__ float t[32][33];
  int c0 = blockIdx.x * 32, r0 = blockIdx.y * 32;
  int tx = threadIdx.x, ty = threadIdx.y;
#pragma unroll
  for (int i = 0; i < 32; i += 8) t[ty + i][tx] = in[(long)(r0 + ty + i) * Cn + c0 + tx];
  __syncthreads();
#pragma unroll
  for (int i = 0; i < 32; i += 8) out[(long)(c0 + ty + i) * R + r0 + tx] = (bf16)t[tx][ty + i];
}

// 3 x (512x512) fp32 transposes -> bf16, z-batched
__global__ void tr_f2b3_k(const float* __restrict__ i0, const float* __restrict__ i1,
                          const float* __restrict__ i2, bf16* __restrict__ outb)
{
  const float* in = blockIdx.z == 0 ? i0 : (blockIdx.z == 1 ? i1 : i2);
  bf16* out = outb + (size_t)blockIdx.z * DMODEL * DMODEL;
  __shared__ float t[32][33];
  int c0 = blockIdx.x * 32, r0 = blockIdx.y * 32;
  int tx = threadIdx.x, ty = threadIdx.y;
#pragma unroll
  for (int i = 0; i < 32; i += 8) t[ty + i][tx] = in[(long)(r0 + ty + i) * DMODEL + c0 + tx];
  __syncthreads();
#pragma unroll
  for (int i = 0; i < 32; i += 8) out[(long)(c0 + ty + i) * DMODEL + r0 + tx] = (bf16)t[tx][ty + i];
}

__global__ void tr_b2b_k(const bf16* __restrict__ in, bf16* __restrict__ out, int R, int Cn)
{
  __shared__ bf16 t[32][34];
  int c0 = blockIdx.x * 32, r0 = blockIdx.y * 32;
  int tx = threadIdx.x, ty = threadIdx.y;
#pragma unroll
  for (int i = 0; i < 32; i += 8) t[ty + i][tx] = in[(long)(r0 + ty + i) * Cn + c0 + tx];
  __syncthreads();
#pragma unroll
  for (int i = 0; i < 32; i += 8) out[(long)(c0 + ty + i) * R + r0 + tx] = t[tx][ty + i];
}

// ---------------- host launch ----------------
extern "C" void kernel_launch(void* const* d_in, const int* in_sizes, int n_in,
                              void* d_out, int out_size, void* d_ws, size_t ws_size,
                              hipStream_t stream)
{
  const float* src = (const float*)d_in[0];
  const float* Wq  = (const float*)d_in[1];
  const float* bq  = (const float*)d_in[2];
  const float* Wk  = (const float*)d_in[3];
  const float* bk  = (const float*)d_in[4];
  const float* Wv  = (const float*)d_in[5];
  const float* bv  = (const float*)d_in[6];
  const float* Er  = (const float*)d_in[7];
  const float* W1  = (const float*)d_in[8];
  const float* b1  = (const float*)d_in[9];
  const float* W2  = (const float*)d_in[10];
  const float* b2  = (const float*)d_in[11];
  const float* g1  = (const float*)d_in[12];
  const float* be1 = (const float*)d_in[13];
  const float* g2  = (const float*)d_in[14];
  const float* be2 = (const float*)d_in[15];

  char* wp = (char*)d_ws;
  auto alloc = [&](size_t bytes) { char* p = wp; wp += (bytes + 255) & ~(size_t)255; return p; };

  bf16* x0b   = (bf16*)alloc((size_t)S * DMODEL * 2);
  bf16* wqkvT = (bf16*)alloc((size_t)3 * DMODEL * DMODEL * 2);
  float* bqkv = (float*)alloc((size_t)3 * DMODEL * 4);
  bf16* w1T   = (bf16*)alloc((size_t)DFF * DMODEL * 2);
  bf16* w2T   = (bf16*)alloc((size_t)DMODEL * DFF * 2);
  bf16* erS   = (bf16*)alloc((size_t)S * DH * 2);
  bf16* qkvb  = (bf16*)alloc((size_t)3 * S * DMODEL * 2);
  bf16* vt    = (bf16*)alloc((size_t)DMODEL * S * 2);
  bf16* qer   = (bf16*)alloc((size_t)NH * S * S * 2);
  float* pO   = (float*)alloc((size_t)NSP * NH * S * DH * 4);
  float* pM   = (float*)alloc((size_t)NSP * NH * S * 4);
  float* pL   = (float*)alloc((size_t)NSP * NH * S * 4);
  float* sa   = (float*)alloc((size_t)S * DMODEL * 4);
  bf16* yb    = (bf16*)alloc((size_t)2 * S * DMODEL * 2);
  bf16* h1    = (bf16*)alloc((size_t)2 * S * DFF * 2);
  float* pFF  = (float*)alloc((size_t)4 * 2 * S * DMODEL * 4);

  const long MN2 = (long)2 * S * DMODEL;
  dim3 tb(32, 8);

  conv_x0_k<<<(S * DMODEL) / 256, 256, 0, stream>>>(src, x0b);
  conv_er_k<<<(S * DH) / 256, 256, 0, stream>>>(Er, erS);
  tr_f2b3_k<<<dim3(DMODEL / 32, DMODEL / 32, 3), tb, 0, stream>>>(Wq, Wk, Wv, wqkvT);
  pack_bias_k<<<6, 256, 0, stream>>>(bq, bk, bv, bqkv);
  tr_f2b_k<<<dim3(DFF / 32, DMODEL / 32), tb, 0, stream>>>(W1, w1T, DMODEL, DFF);
  tr_f2b_k<<<dim3(DMODEL / 32, DFF / 32), tb, 0, stream>>>(W2, w2T, DFF, DMODEL);

  // QKV (batch 0 only), batched z=3; z==0 (Q) pre-scaled by CST
  gemm_k<<<dim3(4, 16, 3), 256, 0, stream>>>(
      x0b, 0, DMODEL, wqkvT, (long)DMODEL * DMODEL, DMODEL,
      qkvb, (long)S * DMODEL, DMODEL, bqkv, DMODEL, 6, S, DMODEL, DMODEL);

  const bf16* qb = qkvb;
  const bf16* kb = qkvb + (long)S * DMODEL;
  const bf16* vb = qkvb + (long)2 * S * DMODEL;

  // V^T
  tr_b2b_k<<<dim3(DMODEL / 32, S / 32), tb, 0, stream>>>(vb, vt, S, DMODEL);

  // QEr[h] = Qscaled_h @ ErS^T  (pre-scaled qer)
  gemm_k<<<dim3(16, 16, 8), 256, 0, stream>>>(
      qb, DH, DMODEL, erS, 0, DH, qer, (long)S * S, S, nullptr, 0, 2, S, S, DH);

  // fused attention
  attn_k<<<dim3(32 * NSP, NH), 256, 0, stream>>>(qb, kb, vt, qer, pO, pM, pL);
  merge_k<<<(S * DMODEL) / 256, 256, 0, stream>>>(pO, pM, pL, sa);

  // LN1 -> y (bf16)
  ln1_k<<<2 * S, 256, 0, stream>>>(src, sa, g1, be1, yb);

  // FFN1: y @ W1^T + b1, relu, bf16
  gemm_k<<<dim3(DFF / 128, (2 * S) / 128, 1), 256, 0, stream>>>(
      yb, 0, DMODEL, w1T, 0, DMODEL, h1, 0, DFF, b1, 0, 3, 2 * S, DFF, DMODEL);

  // FFN2 split-K=4: partials in pFF[z], bias added in ln2
  gemm_k<<<dim3(DMODEL / 128, (2 * S) / 128, 4), 256, 0, stream>>>(
      h1, 512, DFF, w2T, 512, DFF, pFF, MN2, DMODEL, nullptr, 0, 0, 2 * S, DMODEL, 512);

  // LN2 (+partial-sum +b2) -> out
  ln2_k<<<2 * S, 256, 0, stream>>>(yb, pFF, MN2, b2, g2, be2, (float*)d_out);
}

// Round 7
// 171.243 us; speedup vs baseline: 1.0723x; 1.0405x over previous
//
#include <hip/hip_runtime.h>

typedef __bf16 bf16;
typedef __attribute__((ext_vector_type(8))) __bf16 bf16x8;
typedef __attribute__((ext_vector_type(4))) __bf16 bf16x4;
typedef __attribute__((ext_vector_type(4))) float f32x4;

#define S 2048
#define DMODEL 512
#define NH 8
#define DH 64
#define DFF 2048
#define MAXLEN 16384
#define LN_EPS 1e-5f
#define NSP 8
#define CW (S / NSP)
#define BC 64
#define CST 0.18033688f  // (1/8) * log2(e)

__device__ __forceinline__ void gload16(const bf16* g, bf16* l) {
  __builtin_amdgcn_global_load_lds(
      (const __attribute__((address_space(1))) void*)g,
      (__attribute__((address_space(3))) void*)l, 16, 0, 0);
}

// ---------------- m97-style bf16 MFMA GEMM: C = A[M,K] @ Bt[N,K]^T (+bias)(+relu) ----------------
// flags: bit0 = relu, bit1 = bf16 output (else fp32), bit2 = scale z==0 output by CST,
//        bit3 = skew-write guard (skip row==0 && col<N-1; used for direct-Srel materialization)
__global__ __launch_bounds__(256) void gemm_k(
    const bf16* __restrict__ A, long sAz, int lda,
    const bf16* __restrict__ B, long sBz, int ldb,
    void* __restrict__ C, long sCz, int ldc,
    const float* __restrict__ bias, long sBiasZ, int flags,
    int M, int N, int K)
{
  __shared__ bf16 lsA[128 * 32];
  __shared__ bf16 lsB[128 * 32];
  const int z = blockIdx.z;
  A += (long)z * sAz;
  B += (long)z * sBz;
  const int m0 = blockIdx.y * 128, n0 = blockIdx.x * 128;
  const int tid = threadIdx.x;
  const int lane = tid & 63, w = tid >> 6;
  const int wr = (w >> 1) * 64, wc = (w & 1) * 64;
  const int r15 = lane & 15, kg = lane >> 4;
  const int srow = lane >> 2, scol = (lane & 3) * 8;

  const bf16* Ag0 = A + (long)(m0 + 32 * w + srow) * lda + scol;
  const bf16* Ag1 = Ag0 + 16 * lda;
  const bf16* Bg0 = B + (long)(n0 + 32 * w + srow) * ldb + scol;
  const bf16* Bg1 = Bg0 + 16 * ldb;
  bf16* La0 = &lsA[(32 * w + srow) * 32 + scol];
  bf16* La1 = La0 + 16 * 32;
  bf16* Lb0 = &lsB[(32 * w + srow) * 32 + scol];
  bf16* Lb1 = Lb0 + 16 * 32;

  f32x4 acc[4][4] = {};
  for (int k0 = 0; k0 < K; k0 += 32) {
    gload16(Ag0 + k0, La0);
    gload16(Ag1 + k0, La1);
    gload16(Bg0 + k0, Lb0);
    gload16(Bg1 + k0, Lb1);
    __syncthreads();
    bf16x8 af[4], bfr[4];
#pragma unroll
    for (int mi = 0; mi < 4; ++mi) af[mi] = *(const bf16x8*)&lsA[(wr + mi * 16 + r15) * 32 + kg * 8];
#pragma unroll
    for (int ni = 0; ni < 4; ++ni) bfr[ni] = *(const bf16x8*)&lsB[(wc + ni * 16 + r15) * 32 + kg * 8];
    __builtin_amdgcn_s_setprio(1);
#pragma unroll
    for (int mi = 0; mi < 4; ++mi)
#pragma unroll
      for (int ni = 0; ni < 4; ++ni)
        acc[mi][ni] = __builtin_amdgcn_mfma_f32_16x16x32_bf16(af[mi], bfr[ni], acc[mi][ni], 0, 0, 0);
    __builtin_amdgcn_s_setprio(0);
    __syncthreads();
  }
  const float* bz = bias ? bias + (long)z * sBiasZ : nullptr;
  const float scl = ((flags & 4) && z == 0) ? CST : 1.f;
#pragma unroll
  for (int mi = 0; mi < 4; ++mi)
#pragma unroll
    for (int ni = 0; ni < 4; ++ni) {
      int col = n0 + wc + ni * 16 + r15;
      float bv = bz ? bz[col] : 0.f;
#pragma unroll
      for (int r = 0; r < 4; ++r) {
        int row = m0 + wr + mi * 16 + kg * 4 + r;
        if ((flags & 8) && row == 0 && col < N - 1) continue;
        float v = (acc[mi][ni][r] + bv) * scl;
        if (flags & 1) v = fmaxf(v, 0.f);
        if (flags & 2) ((bf16*)C)[(long)z * sCz + (long)row * ldc + col] = (bf16)v;
        else           ((float*)C)[(long)z * sCz + (long)row * ldc + col] = v;
      }
    }
}

// zero the skew diagonal: Srel[h][r][r+1] = 0  (flat h*S*S + r*(S+1) + 1), r in [0, S-1)
__global__ __launch_bounds__(256) void zdiag_k(bf16* __restrict__ srel)
{
  int i = blockIdx.x * 256 + threadIdx.x;
  if (i >= NH * (S - 1)) return;
  int h = i / (S - 1), rg = i - h * (S - 1);
  srel[(long)h * S * S + (long)rg * (S + 1) + 1] = (bf16)0.f;
}

// ---------------- fused attention v5 ----------------
// swapped QK (lane = one q-row), swapped PV (O^T, lane-local alpha), pre-skewed Srel
// staged as an aligned 64x64 tile (overlaid with per-wave P), reg-prefetch of next tile.
// grid (32*NSP, NH): rb = bx>>3 (64-row block), sp = bx&7 (column slice of 256)
__global__ __launch_bounds__(256, 5) void attn_k(
    const bf16* __restrict__ qg, const bf16* __restrict__ kgl, const bf16* __restrict__ vtg,
    const bf16* __restrict__ srel,
    bf16* __restrict__ pO, float* __restrict__ pM, float* __restrict__ pL)
{
  __shared__ bf16 Kl[64 * 72];   // K tile [c][k]
  __shared__ bf16 Vl[64 * 72];   // V^T tile [d][c]
  __shared__ bf16 SP[64 * 72];   // Srel tile [q][c]; per-wave rows overwritten by P after use
  const int bx = blockIdx.x, h = blockIdx.y;
  const int rb = bx >> 3, sp = bx & 7;
  const int r0 = rb * 64;
  const int cb = sp * CW;
  const int tid = threadIdx.x, lane = tid & 63, w = tid >> 6;
  const int r15 = lane & 15, g = lane >> 4;
  const long hb = (long)h * S * S;

  // persistent Q frags (B-operand of QK): row = r0+16w+r15, k = g*8..
  bf16x8 qf0, qf1;
  {
    const bf16* qrow = qg + (long)(r0 + w * 16 + r15) * DMODEL + h * DH;
    qf0 = *(const bf16x8*)&qrow[g * 8];
    qf1 = *(const bf16x8*)&qrow[32 + g * 8];
  }
  f32x4 Oacc[4] = {};           // O^T: Oacc[no][r] = O[q = w*16+r15][d = no*16+4g+r]
  float m2 = -1e30f, l2 = 0.f;  // softmax state for q-row w*16+r15

  const int myrow = w * 16 + r15;
  const int rg = r0 + myrow;

  // staging geometry: each thread stages 2 rows of K, V^T, Srel (16B chunks)
  const int kRow = tid >> 3, kCh = (tid & 7) * 8;
  bf16x8 kf0, kf1, vf0, vf1, sf0, sf1;

  auto LOADR = [&](int c0) {
    kf0 = *(const bf16x8*)&kgl[(long)(c0 + kRow) * DMODEL + h * DH + kCh];
    kf1 = *(const bf16x8*)&kgl[(long)(c0 + kRow + 32) * DMODEL + h * DH + kCh];
    vf0 = *(const bf16x8*)&vtg[(long)(h * DH + kRow) * S + c0 + kCh];
    vf1 = *(const bf16x8*)&vtg[(long)(h * DH + kRow + 32) * S + c0 + kCh];
    sf0 = *(const bf16x8*)&srel[hb + (long)(r0 + kRow) * S + c0 + kCh];
    sf1 = *(const bf16x8*)&srel[hb + (long)(r0 + kRow + 32) * S + c0 + kCh];
  };
  auto STORE = [&]() {
    *(bf16x8*)&Kl[kRow * 72 + kCh] = kf0;
    *(bf16x8*)&Kl[(kRow + 32) * 72 + kCh] = kf1;
    *(bf16x8*)&Vl[kRow * 72 + kCh] = vf0;
    *(bf16x8*)&Vl[(kRow + 32) * 72 + kCh] = vf1;
    *(bf16x8*)&SP[kRow * 72 + kCh] = sf0;
    *(bf16x8*)&SP[(kRow + 32) * 72 + kCh] = sf1;
  };

  LOADR(cb);
#pragma unroll
  for (int t = 0; t < CW / BC; ++t) {
    __syncthreads();           // all waves done with prev tile's LDS (incl. P reads)
    STORE();
    if (t + 1 < CW / BC) LOADR(cb + (t + 1) * BC);  // prefetch next tile
    __syncthreads();           // LDS ready

    // QK^T swapped: sc[ni][r] = score[q = myrow][c-local = ni*16 + 4g + r]
    f32x4 sc[4];
    __builtin_amdgcn_s_setprio(1);
#pragma unroll
    for (int ni = 0; ni < 4; ++ni) {
      bf16x8 k0f = *(const bf16x8*)&Kl[(ni * 16 + r15) * 72 + g * 8];
      bf16x8 k1f = *(const bf16x8*)&Kl[(ni * 16 + r15) * 72 + 32 + g * 8];
      f32x4 a = {};
      a = __builtin_amdgcn_mfma_f32_16x16x32_bf16(k0f, qf0, a, 0, 0, 0);
      a = __builtin_amdgcn_mfma_f32_16x16x32_bf16(k1f, qf1, a, 0, 0, 0);
      sc[ni] = a;
    }
    __builtin_amdgcn_s_setprio(0);

    // srel add: aligned b64 reads from own row of the pre-skewed tile
    const bf16* Sw = &SP[myrow * 72];
#pragma unroll
    for (int ni = 0; ni < 4; ++ni) {
      bf16x4 sv = *(const bf16x4*)&Sw[ni * 16 + 4 * g];
#pragma unroll
      for (int r = 0; r < 4; ++r) sc[ni][r] += (float)sv[r];
    }

    // online softmax (base-2), per-lane q-row
    float tmax = sc[0][0];
#pragma unroll
    for (int ni = 0; ni < 4; ++ni)
#pragma unroll
      for (int r = 0; r < 4; ++r) tmax = fmaxf(tmax, sc[ni][r]);
    tmax = fmaxf(tmax, __shfl_xor(tmax, 16));
    tmax = fmaxf(tmax, __shfl_xor(tmax, 32));

    float mn = fmaxf(m2, tmax);
    float al = exp2f(m2 - mn);
    m2 = mn;
    float tsum = 0.f;
#pragma unroll
    for (int ni = 0; ni < 4; ++ni)
#pragma unroll
      for (int r = 0; r < 4; ++r) {
        float p = exp2f(sc[ni][r] - m2);
        sc[ni][r] = p;
        tsum += p;
      }
    tsum += __shfl_xor(tsum, 16);
    tsum += __shfl_xor(tsum, 32);
    l2 = l2 * al + tsum;

    // rescale O^T: q-index of Oacc is r15 == softmax row -> own-lane alpha
#pragma unroll
    for (int no = 0; no < 4; ++no)
#pragma unroll
      for (int r = 0; r < 4; ++r) Oacc[no][r] *= al;

    // write P over own row of SP (srel already consumed), then PV
    bf16* Pw = &SP[myrow * 72];
#pragma unroll
    for (int ni = 0; ni < 4; ++ni) {
      bf16x4 pv = { (bf16)sc[ni][0], (bf16)sc[ni][1], (bf16)sc[ni][2], (bf16)sc[ni][3] };
      *(bf16x4*)&Pw[ni * 16 + 4 * g] = pv;
    }

    __builtin_amdgcn_s_setprio(1);
#pragma unroll
    for (int kc = 0; kc < 2; ++kc) {
      bf16x8 pf = *(const bf16x8*)&SP[(w * 16 + r15) * 72 + kc * 32 + g * 8];
#pragma unroll
      for (int no = 0; no < 4; ++no) {
        bf16x8 av = *(const bf16x8*)&Vl[(no * 16 + r15) * 72 + kc * 32 + g * 8];
        Oacc[no] = __builtin_amdgcn_mfma_f32_16x16x32_bf16(av, pf, Oacc[no], 0, 0, 0);
      }
    }
    __builtin_amdgcn_s_setprio(0);
  }

  // write partials (bf16 O^T, vectorized)
  const long ob = ((long)sp * NH + h) * S * DH;
  const long qrow_g = r0 + w * 16 + r15;
#pragma unroll
  for (int no = 0; no < 4; ++no) {
    bf16x4 ov = { (bf16)Oacc[no][0], (bf16)Oacc[no][1], (bf16)Oacc[no][2], (bf16)Oacc[no][3] };
    *(bf16x4*)&pO[ob + qrow_g * DH + no * 16 + 4 * g] = ov;
  }
  if (g == 0) {
    const long sb = ((long)sp * NH + h) * S;
    pM[sb + rg] = m2;
    pL[sb + rg] = l2;
  }
}

// ---------------- merge the NSP column-slice partials -> sa[r][DMODEL] (f32) ----------------
__global__ __launch_bounds__(256) void merge_k(
    const bf16* __restrict__ pO, const float* __restrict__ pM, const float* __restrict__ pL,
    float* __restrict__ sa)
{
  int i = blockIdx.x * 256 + threadIdx.x;
  int r = i >> 9, col = i & 511;
  int h = col >> 6, d = col & 63;
  long i0 = (long)h * S + r;
  float mm = -1e30f;
  float ms[NSP];
#pragma unroll
  for (int s = 0; s < NSP; ++s) { ms[s] = pM[(long)s * NH * S + i0]; mm = fmaxf(mm, ms[s]); }
  float num = 0.f, den = 0.f;
#pragma unroll
  for (int s = 0; s < NSP; ++s) {
    float e = exp2f(ms[s] - mm);
    den += pL[(long)s * NH * S + i0] * e;
    num += (float)pO[(long)s * NH * S * DH + i0 * DH + d] * e;
  }
  sa[(long)r * DMODEL + col] = num / den;
}

// ---------------- layernorms ----------------
__device__ __forceinline__ float blk_sum(float v, float* red) {
  for (int o = 32; o; o >>= 1) v += __shfl_xor(v, o);
  int tid = threadIdx.x;
  if ((tid & 63) == 0) red[tid >> 6] = v;
  __syncthreads();
  v = red[0] + red[1] + red[2] + red[3];
  __syncthreads();
  return v;
}

__global__ __launch_bounds__(256) void ln1_k(
    const float* __restrict__ src, const float* __restrict__ sa,
    const float* __restrict__ g, const float* __restrict__ be, bf16* __restrict__ y)
{
  __shared__ float red[4];
  const int row = blockIdx.x;
  const int b = row >> 11, s2 = row & 2047;
  const float* xs = src + (long)s2 * (2 * DMODEL) + b * DMODEL;
  const float* ss = sa + (long)s2 * DMODEL;
  const int tid = threadIdx.x;
  float a0 = xs[tid] + ss[tid];
  float a1 = xs[tid + 256] + ss[tid + 256];
  float sum = blk_sum(a0 + a1, red);
  float sq  = blk_sum(a0 * a0 + a1 * a1, red);
  float mu = sum * (1.f / DMODEL);
  float var = sq * (1.f / DMODEL) - mu * mu;
  float rs = rsqrtf(var + LN_EPS);
  y[(long)row * DMODEL + tid]       = (bf16)((a0 - mu) * rs * g[tid] + be[tid]);
  y[(long)row * DMODEL + tid + 256] = (bf16)((a1 - mu) * rs * g[tid + 256] + be[tid + 256]);
}

// out = LN( y + sum_4(pFF) + b2 ) ; pFF are split-K partials
__global__ __launch_bounds__(256) void ln2_k(
    const bf16* __restrict__ y, const float* __restrict__ pFF, long pStride,
    const float* __restrict__ b2,
    const float* __restrict__ g, const float* __restrict__ be, float* __restrict__ out)
{
  __shared__ float red[4];
  const int row = blockIdx.x;
  const int b = row >> 11, s2 = row & 2047;
  const int tid = threadIdx.x;
  long i0 = (long)row * DMODEL + tid;
  long i1 = i0 + 256;
  float f0 = pFF[i0] + pFF[i0 + pStride] + pFF[i0 + 2 * pStride] + pFF[i0 + 3 * pStride] + b2[tid];
  float f1 = pFF[i1] + pFF[i1 + pStride] + pFF[i1 + 2 * pStride] + pFF[i1 + 3 * pStride] + b2[tid + 256];
  float a0 = (float)y[i0] + f0;
  float a1 = (float)y[i1] + f1;
  float sum = blk_sum(a0 + a1, red);
  float sq  = blk_sum(a0 * a0 + a1 * a1, red);
  float mu = sum * (1.f / DMODEL);
  float var = sq * (1.f / DMODEL) - mu * mu;
  float rs = rsqrtf(var + LN_EPS);
  float* o = out + (long)s2 * (2 * DMODEL) + b * DMODEL;
  o[tid]       = (a0 - mu) * rs * g[tid] + be[tid];
  o[tid + 256] = (a1 - mu) * rs * g[tid + 256] + be[tid + 256];
}

// ---------------- converts / transposes ----------------
__global__ __launch_bounds__(256) void conv_x0_k(const float* __restrict__ src, bf16* __restrict__ x0b)
{
  long i = (long)blockIdx.x * 256 + threadIdx.x;
  int s2 = (int)(i >> 9), d = (int)(i & 511);
  x0b[i] = (bf16)src[(long)s2 * (2 * DMODEL) + d];
}

__global__ __launch_bounds__(256) void conv_er_k(const float* __restrict__ Er, bf16* __restrict__ erS)
{
  long i = (long)blockIdx.x * 256 + threadIdx.x;
  erS[i] = (bf16)Er[(long)(MAXLEN - S) * DH + i];
}

__global__ __launch_bounds__(256) void pack_bias_k(
    const float* __restrict__ a, const float* __restrict__ b, const float* __restrict__ c,
    float* __restrict__ o)
{
  int t = blockIdx.x * 256 + threadIdx.x;
  o[t] = t < 512 ? a[t] : (t < 1024 ? b[t - 512] : c[t - 1024]);
}

__global__ void tr_f2b_k(const float* __restrict__ in, bf16* __restrict__ out, int R, int Cn)
{
  __shared__ float t[32][33];
  int c0 = blockIdx.x * 32, r0 = blockIdx.y * 32;
  int tx = threadIdx.x, ty = threadIdx.y;
#pragma unroll
  for (int i = 0; i < 32; i += 8) t[ty + i][tx] = in[(long)(r0 + ty + i) * Cn + c0 + tx];
  __syncthreads();
#pragma unroll
  for (int i = 0; i < 32; i += 8) out[(long)(c0 + ty + i) * R + r0 + tx] = (bf16)t[tx][ty + i];
}

// 3 x (512x512) fp32 transposes -> bf16, z-batched
__global__ void tr_f2b3_k(const float* __restrict__ i0, const float* __restrict__ i1,
                          const float* __restrict__ i2, bf16* __restrict__ outb)
{
  const float* in = blockIdx.z == 0 ? i0 : (blockIdx.z == 1 ? i1 : i2);
  bf16* out = outb + (size_t)blockIdx.z * DMODEL * DMODEL;
  __shared__ float t[32][33];
  int c0 = blockIdx.x * 32, r0 = blockIdx.y * 32;
  int tx = threadIdx.x, ty = threadIdx.y;
#pragma unroll
  for (int i = 0; i < 32; i += 8) t[ty + i][tx] = in[(long)(r0 + ty + i) * DMODEL + c0 + tx];
  __syncthreads();
#pragma unroll
  for (int i = 0; i < 32; i += 8) out[(long)(c0 + ty + i) * DMODEL + r0 + tx] = (bf16)t[tx][ty + i];
}

__global__ void tr_b2b_k(const bf16* __restrict__ in, bf16* __restrict__ out, int R, int Cn)
{
  __shared__ bf16 t[32][34];
  int c0 = blockIdx.x * 32, r0 = blockIdx.y * 32;
  int tx = threadIdx.x, ty = threadIdx.y;
#pragma unroll
  for (int i = 0; i < 32; i += 8) t[ty + i][tx] = in[(long)(r0 + ty + i) * Cn + c0 + tx];
  __syncthreads();
#pragma unroll
  for (int i = 0; i < 32; i += 8) out[(long)(c0 + ty + i) * R + r0 + tx] = t[tx][ty + i];
}

// ---------------- host launch ----------------
extern "C" void kernel_launch(void* const* d_in, const int* in_sizes, int n_in,
                              void* d_out, int out_size, void* d_ws, size_t ws_size,
                              hipStream_t stream)
{
  const float* src = (const float*)d_in[0];
  const float* Wq  = (const float*)d_in[1];
  const float* bq  = (const float*)d_in[2];
  const float* Wk  = (const float*)d_in[3];
  const float* bk  = (const float*)d_in[4];
  const float* Wv  = (const float*)d_in[5];
  const float* bv  = (const float*)d_in[6];
  const float* Er  = (const float*)d_in[7];
  const float* W1  = (const float*)d_in[8];
  const float* b1  = (const float*)d_in[9];
  const float* W2  = (const float*)d_in[10];
  const float* b2  = (const float*)d_in[11];
  const float* g1  = (const float*)d_in[12];
  const float* be1 = (const float*)d_in[13];
  const float* g2  = (const float*)d_in[14];
  const float* be2 = (const float*)d_in[15];

  char* wp = (char*)d_ws;
  auto alloc = [&](size_t bytes) { char* p = wp; wp += (bytes + 255) & ~(size_t)255; return p; };

  bf16* x0b   = (bf16*)alloc((size_t)S * DMODEL * 2);
  bf16* wqkvT = (bf16*)alloc((size_t)3 * DMODEL * DMODEL * 2);
  float* bqkv = (float*)alloc((size_t)3 * DMODEL * 4);
  bf16* w1T   = (bf16*)alloc((size_t)DFF * DMODEL * 2);
  bf16* w2T   = (bf16*)alloc((size_t)DMODEL * DFF * 2);
  bf16* erS   = (bf16*)alloc((size_t)S * DH * 2);
  bf16* qkvb  = (bf16*)alloc((size_t)3 * S * DMODEL * 2);
  bf16* vt    = (bf16*)alloc((size_t)DMODEL * S * 2);
  bf16* srel  = (bf16*)alloc((size_t)NH * S * S * 2);
  bf16* pO    = (bf16*)alloc((size_t)NSP * NH * S * DH * 2);
  float* pM   = (float*)alloc((size_t)NSP * NH * S * 4);
  float* pL   = (float*)alloc((size_t)NSP * NH * S * 4);
  float* sa   = (float*)alloc((size_t)S * DMODEL * 4);
  bf16* yb    = (bf16*)alloc((size_t)2 * S * DMODEL * 2);
  bf16* h1    = (bf16*)alloc((size_t)2 * S * DFF * 2);
  float* pFF  = (float*)alloc((size_t)4 * 2 * S * DMODEL * 4);

  const long MN2 = (long)2 * S * DMODEL;
  dim3 tb(32, 8);

  conv_x0_k<<<(S * DMODEL) / 256, 256, 0, stream>>>(src, x0b);
  conv_er_k<<<(S * DH) / 256, 256, 0, stream>>>(Er, erS);
  tr_f2b3_k<<<dim3(DMODEL / 32, DMODEL / 32, 3), tb, 0, stream>>>(Wq, Wk, Wv, wqkvT);
  pack_bias_k<<<6, 256, 0, stream>>>(bq, bk, bv, bqkv);
  tr_f2b_k<<<dim3(DFF / 32, DMODEL / 32), tb, 0, stream>>>(W1, w1T, DMODEL, DFF);
  tr_f2b_k<<<dim3(DMODEL / 32, DFF / 32), tb, 0, stream>>>(W2, w2T, DFF, DMODEL);

  // QKV (batch 0 only), batched z=3; z==0 (Q) pre-scaled by CST
  gemm_k<<<dim3(4, 16, 3), 256, 0, stream>>>(
      x0b, 0, DMODEL, wqkvT, (long)DMODEL * DMODEL, DMODEL,
      qkvb, (long)S * DMODEL, DMODEL, bqkv, DMODEL, 6, S, DMODEL, DMODEL);

  const bf16* qb = qkvb;
  const bf16* kb = qkvb + (long)S * DMODEL;
  const bf16* vb = qkvb + (long)2 * S * DMODEL;

  // V^T
  tr_b2b_k<<<dim3(DMODEL / 32, S / 32), tb, 0, stream>>>(vb, vt, S, DMODEL);

  // Srel materialized directly: C[rg][e] -> flat rg*(S+1) + e - (S-1)
  // (ldc = S+1, base offset -(S-1), row-0 guard via flags bit3); diagonal zeros via zdiag_k.
  zdiag_k<<<(NH * (S - 1) + 255) / 256, 256, 0, stream>>>(srel);
  gemm_k<<<dim3(16, 16, 8), 256, 0, stream>>>(
      qb, DH, DMODEL, erS, 0, DH, (void*)(srel - (S - 1)), (long)S * S, S + 1,
      nullptr, 0, 2 | 8, S, S, DH);

  // fused attention (reads pre-skewed Srel rows directly)
  attn_k<<<dim3(32 * NSP, NH), 256, 0, stream>>>(qb, kb, vt, srel, pO, pM, pL);
  merge_k<<<(S * DMODEL) / 256, 256, 0, stream>>>(pO, pM, pL, sa);

  // LN1 -> y (bf16)
  ln1_k<<<2 * S, 256, 0, stream>>>(src, sa, g1, be1, yb);

  // FFN1: y @ W1^T + b1, relu, bf16
  gemm_k<<<dim3(DFF / 128, (2 * S) / 128, 1), 256, 0, stream>>>(
      yb, 0, DMODEL, w1T, 0, DMODEL, h1, 0, DFF, b1, 0, 3, 2 * S, DFF, DMODEL);

  // FFN2 split-K=4: partials in pFF[z], bias added in ln2
  gemm_k<<<dim3(DMODEL / 128, (2 * S) / 128, 4), 256, 0, stream>>>(
      h1, 512, DFF, w2T, 512, DFF, pFF, MN2, DMODEL, nullptr, 0, 0, 2 * S, DMODEL, 512);

  // LN2 (+partial-sum +b2) -> out
  ln2_k<<<2 * S, 256, 0, stream>>>(yb, pFF, MN2, b2, g2, be2, (float*)d_out);
}